// Round 6
// baseline (921.986 us; speedup 1.0000x reference)
//
#include <hip/hip_runtime.h>
#include <math.h>

// ---------- config ----------
#define T_TOK 4096
#define DIM   2048
#define NEXP  32
#define TOPK  4
#define CAP   160          // ceil(1.25*4096/32)
#define ECAP  (NEXP*CAP)   // 5120
#define ISZ   1024         // moe intermediate
#define ISH   2048         // shared intermediate (I*NSH)

typedef short bf16x8 __attribute__((ext_vector_type(8)));
typedef float f32x4  __attribute__((ext_vector_type(4)));

__device__ __forceinline__ unsigned int f2bf(float f){
  union { float f; unsigned int u; } v; v.f = f;
  return (v.u + 0x7fffu + ((v.u >> 16) & 1u)) >> 16;   // RNE
}

// async global->LDS, 16B/lane; LDS base wave-uniform (HW adds lane*16), global addr per-lane
#define GLOAD16(g, l) __builtin_amdgcn_global_load_lds( \
    (const __attribute__((address_space(1))) unsigned int*)(g), \
    (__attribute__((address_space(3))) unsigned int*)(l), 16, 0, 0)

// ---------- fp32 -> bf16 convert (layout-preserving) ----------
__global__ __launch_bounds__(256) void cvt_k(const float* __restrict__ in,
                                             unsigned short* __restrict__ out, int n8){
  int i = blockIdx.x*256 + threadIdx.x;
  if (i >= n8) return;
  const float4 a = *(const float4*)&in[(size_t)i*8];
  const float4 b = *(const float4*)&in[(size_t)i*8 + 4];
  uint4 v;
  v.x = f2bf(a.x) | (f2bf(a.y) << 16);
  v.y = f2bf(a.z) | (f2bf(a.w) << 16);
  v.z = f2bf(b.x) | (f2bf(b.y) << 16);
  v.w = f2bf(b.z) | (f2bf(b.w) << 16);
  *(uint4*)&out[(size_t)i*8] = v;
}

// ---------- fp32 [R,C] -> bf16 [C,R] transpose-convert, per expert (blockIdx.z) ----------
// 128x128 tiles; LDS XOR-swizzle byte ^= (r&31)<<2 makes both phases ~conflict-free.
template<int R, int C>
__global__ __launch_bounds__(256) void tcvt_k(const float* __restrict__ src,
                                              unsigned short* __restrict__ dst){
  __shared__ unsigned short tile[128*128];
  const int tid = threadIdx.x;
  const size_t eoff = (size_t)blockIdx.z * R * C;
  const int tj = blockIdx.x, ti = blockIdx.y;   // col-tile, row-tile of src
  const float* s = src + eoff + (size_t)(ti*128)*C + tj*128;
  #pragma unroll
  for (int q = 0; q < 16; ++q){
    int flat = q*256 + tid;
    int r = flat >> 5, c4 = (flat & 31) << 2;
    float4 f = *(const float4*)&s[(size_t)r*C + c4];
    unsigned int w0 = f2bf(f.x) | (f2bf(f.y) << 16);
    unsigned int w1 = f2bf(f.z) | (f2bf(f.w) << 16);
    int b = r*256 + ((c4*2) ^ ((r & 31) << 2));
    *(unsigned int*)((char*)tile + b) = w0;
    *(unsigned int*)((char*)tile + (b ^ 4)) = w1;
  }
  __syncthreads();
  unsigned short* d = dst + eoff;
  #pragma unroll
  for (int q = 0; q < 32; ++q){
    int flat = q*256 + tid;
    int oc = flat >> 6;             // src col within tile
    int c2 = (flat & 63) << 1;      // src row pair
    int b0 = c2*256     + ((oc*2) ^ (( c2    & 31) << 2));
    int b1 = (c2+1)*256 + ((oc*2) ^ (((c2+1) & 31) << 2));
    unsigned int lo = *(const unsigned short*)((const char*)tile + b0);
    unsigned int hi = *(const unsigned short*)((const char*)tile + b1);
    *(unsigned int*)&d[(size_t)(tj*128 + oc)*R + ti*128 + c2] = lo | (hi << 16);
  }
}

// ---------- router: fp64 logits, exact top-k semantics ----------
__global__ __launch_bounds__(256) void router_k(const float* __restrict__ x,
                                                const float* __restrict__ rw,
                                                const float* __restrict__ eb,
                                                int* __restrict__ tki,
                                                float* __restrict__ tkw){
  __shared__ float  xs[4][DIM];
  __shared__ double ssh[4][NEXP];
  const int tb = blockIdx.x * 4;
  const int tid = threadIdx.x;
  for (int i = tid; i < 4*(DIM/4); i += 256){
    int t = i >> 9, c = (i & 511) << 2;
    *(float4*)&xs[t][c] = *(const float4*)&x[(size_t)(tb + t)*DIM + c];
  }
  __syncthreads();
  const int lane = tid & 63, wv = tid >> 6;
  for (int ei = 0; ei < 8; ++ei){
    int e = wv*8 + ei;
    double a0=0, a1=0, a2=0, a3=0;
    for (int d = lane; d < DIM; d += 64){
      double w = (double)rw[(size_t)e*DIM + d];
      a0 += (double)xs[0][d] * w;
      a1 += (double)xs[1][d] * w;
      a2 += (double)xs[2][d] * w;
      a3 += (double)xs[3][d] * w;
    }
    for (int off = 32; off; off >>= 1){
      a0 += __shfl_down(a0, off);
      a1 += __shfl_down(a1, off);
      a2 += __shfl_down(a2, off);
      a3 += __shfl_down(a3, off);
    }
    if (lane == 0){ ssh[0][e]=a0; ssh[1][e]=a1; ssh[2][e]=a2; ssh[3][e]=a3; }
  }
  __syncthreads();
  if (tid < 4){
    const int t = tid;
    double s[NEXP], sc[NEXP];
    for (int e = 0; e < NEXP; ++e){
      double sig = 1.0 / (1.0 + exp(-ssh[t][e]));
      s[e] = sig; sc[e] = sig + (double)eb[e];
    }
    double gsc[8];
    for (int g = 0; g < 8; ++g){
      double b0=sc[g*4],b1=sc[g*4+1],b2=sc[g*4+2],b3=sc[g*4+3];
      double h1=fmax(b0,b1), l1=fmin(b0,b1);
      double h2=fmax(b2,b3), l2=fmin(b2,b3);
      double top = fmax(h1,h2);
      double sec = fmax(fmin(h1,h2), (h1 >= h2) ? l1 : l2);
      gsc[g] = top + sec;
    }
    int gsel = 0;
    for (int r = 0; r < 3; ++r){
      int bi = -1; double bv = -1e300;
      for (int g = 0; g < 8; ++g)
        if (!((gsel >> g) & 1) && gsc[g] > bv){ bv = gsc[g]; bi = g; }
      gsel |= 1 << bi;
    }
    double mval[NEXP];
    for (int e = 0; e < NEXP; ++e)
      mval[e] = ((gsel >> (e >> 2)) & 1) ? sc[e] : 0.0;
    int idx4[4]; double wsum = 0.0, wv4[4];
    for (int r = 0; r < 4; ++r){
      int bi = -1; double bv = -1e300;
      for (int e = 0; e < NEXP; ++e)
        if (mval[e] > bv){ bv = mval[e]; bi = e; }
      idx4[r] = bi; mval[bi] = -1e300;
      wv4[r] = s[bi]; wsum += wv4[r];
    }
    const int gt = tb + t;
    for (int r = 0; r < 4; ++r){
      tki[gt*4 + r] = idx4[r];
      tkw[gt*4 + r] = (float)(wv4[r] / (wsum + 1e-20) * 2.5);
    }
  }
}

// ---------- dispatch: wave per expert, stable-order rank scan ----------
__global__ __launch_bounds__(1024) void dispatch_k(const int* __restrict__ tki,
                                                   const float* __restrict__ tkw,
                                                   int* __restrict__ stok,
                                                   float* __restrict__ sw){
  const int e = blockIdx.x*16 + (threadIdx.x >> 6);
  const int lane = threadIdx.x & 63;
  int base = 0;
  for (int it = 0; it < (T_TOK*TOPK)/64; ++it){
    if (base >= CAP) break;
    int idx = it*64 + lane;
    int ex = tki[idx];
    bool m = (ex == e);
    unsigned long long mk = __ballot(m);
    int pos = base + __popcll(mk & ((1ull << lane) - 1ull));
    if (m && pos < CAP){
      stok[e*CAP + pos] = idx >> 2;
      sw[e*CAP + pos]   = tkw[idx];
    }
    base += __popcll(mk);
  }
}

// ---------- MFMA GEMM: 3-deep pipeline, counted vmcnt, 1 barrier/step ----------
// A: bf16 [M,KK] (EXPERT&&GU: rows gathered via stok). B: bf16 [N,KK].
// GU=1: H(bf16)=silu(A@Bg^T)*(A@Bu^T), 32+32 cols/block.
// GU=0: out(f32)=A@B^T, 64 cols/block (EXPERT: scaled atomic scatter).
// Plane LDS (16 rows x 32k = 1KB, chunk==lane): conflict-free, matches gload_lds.
// Pipeline: stage(t+2) issued after barrier t; per-wave counted vmcnt keeps
// ~2 steps of loads in flight (never drains to 0 inside the loop).
template<int EXPERT, int GU>
__global__ __launch_bounds__(256, EXPERT ? 3 : 4)
void gemm6_k(const unsigned short* __restrict__ Ab,
             const unsigned short* __restrict__ B0,
             const unsigned short* __restrict__ B1,
             void* __restrict__ Co,
             const int* __restrict__ stok, const float* __restrict__ sw){
  constexpr int BM   = EXPERT ? 160 : 128;
  constexpr int APL  = BM/16;                 // A planes (10 / 8)
  constexpr int FM   = APL/2;                 // A frags per wave
  constexpr int KK   = GU ? DIM : (EXPERT ? ISZ : ISH);
  constexpr int LDC  = GU ? (EXPERT ? ISZ : ISH) : DIM;
  constexpr int PL   = APL + 4;               // planes per buffer (14 / 12)
  constexpr int NE   = GU ? ISZ : DIM;        // expert B rows per expert
  constexpr int NT   = KK/32;
  constexpr int SMAX = (PL + 3)/4;            // stage slots per wave (4 / 3)
  constexpr int NNB  = GU ? ((EXPERT ? ISZ : ISH)/32) : (DIM/64);

  __shared__ uint4 lds[3][PL*64];

  const int tid  = threadIdx.x;
  const int lane = tid & 63, wid = tid >> 6;

  // block mapping: expert -> same-expert adjacent (A-tile L2 reuse);
  //                shared -> same-n adjacent (weight-slice L2 reuse)
  const int bid = blockIdx.x;
  int grp, nblk;
  if constexpr (EXPERT){ grp = bid >> 5; nblk = bid & 31; }
  else                 { grp = bid & 31; nblk = bid >> 5; }
  const int e  = grp;
  const int mb = EXPERT ? grp*CAP : grp*BM;

  // ---- per-wave plane list + per-lane global pointers ----
  const unsigned short* uptr[SMAX];
  int pl[SMAX];
  #pragma unroll
  for (int i = 0; i < SMAX; ++i){
    int p = wid + i*4;
    pl[i] = (p < PL) ? p : 0;
    int pp = pl[i];
    if (pp < APL){
      int row = pp*16 + (lane & 15);
      int tr;
      if constexpr (EXPERT && GU) tr = stok[mb + row];
      else                        tr = mb + row;
      uptr[i] = Ab + (size_t)tr*KK + (lane >> 4)*8;
    } else {
      int pc = pp - APL;
      const unsigned short* src = (GU && pc >= 2) ? B1 : B0;
      int col = (GU ? (nblk*32 + (pc & 1)*16) : (nblk*64 + pc*16)) + (lane & 15);
      size_t rg = EXPERT ? ((size_t)e*NE + col) : (size_t)col;
      uptr[i] = src + rg*KK + (lane >> 4)*8;
    }
  }

  auto stage = [&](int k0, int bi){
    char* base = (char*)&lds[bi][0];
    #pragma unroll
    for (int i = 0; i < SMAX; ++i){
      if (i*4 + wid < PL)                   // wave-uniform
        GLOAD16(uptr[i] + k0, base + pl[i]*1024);
    }
  };

  // ---- compute-side plane assignment ----
  const int wn  = wid & 1;
  const int wmp = (wid >> 1) * FM;
  const int bp0 = APL + (GU ? wn       : 2*wn);
  const int bp1 = APL + (GU ? (2 + wn) : (2*wn + 1));

  f32x4 acc[FM][2];
  #pragma unroll
  for (int i = 0; i < FM; ++i){ acc[i][0] = f32x4{0,0,0,0}; acc[i][1] = f32x4{0,0,0,0}; }

  // prologue: two stages in flight
  stage(0, 0);
  stage(32, 1);

  int cons = 0;
  for (int t = 0; t < NT; ++t){
    // counted wait: stage t landed, stage t+1 (S_w loads) may stay in flight
    if (t == NT - 1){
      asm volatile("s_waitcnt vmcnt(0)" ::: "memory");
    } else if constexpr (EXPERT){
      if (wid < 2) asm volatile("s_waitcnt vmcnt(4)" ::: "memory");
      else         asm volatile("s_waitcnt vmcnt(3)" ::: "memory");
    } else {
      asm volatile("s_waitcnt vmcnt(3)" ::: "memory");
    }
    __builtin_amdgcn_s_barrier();
    __builtin_amdgcn_sched_barrier(0);

    if (t + 2 < NT){
      int stg = cons + 2; if (stg >= 3) stg -= 3;
      stage((t + 2)*32, stg);
    }

    const char* L = (const char*)&lds[cons][0];
    bf16x8 af[FM];
    #pragma unroll
    for (int i = 0; i < FM; ++i)
      af[i] = *(const bf16x8*)(L + (wmp + i)*1024 + lane*16);
    bf16x8 bf0 = *(const bf16x8*)(L + bp0*1024 + lane*16);
    bf16x8 bf1 = *(const bf16x8*)(L + bp1*1024 + lane*16);
    #pragma unroll
    for (int i = 0; i < FM; ++i){
      acc[i][0] = __builtin_amdgcn_mfma_f32_16x16x32_bf16(af[i], bf0, acc[i][0], 0, 0, 0);
      acc[i][1] = __builtin_amdgcn_mfma_f32_16x16x32_bf16(af[i], bf1, acc[i][1], 0, 0, 0);
    }
    cons = (cons == 2) ? 0 : cons + 1;
  }

  // ---- epilogue ----
  const int r16 = lane & 15, rg = (lane >> 4) * 4;
  #pragma unroll
  for (int i = 0; i < FM; ++i){
    #pragma unroll
    for (int r = 0; r < 4; ++r){
      const int m = wmp*16 + i*16 + rg + r;
      if constexpr (GU){
        float g = acc[i][0][r], u = acc[i][1][r];
        float h = g / (1.f + __expf(-g)) * u;
        int c = nblk*32 + wn*16 + r16;
        ((unsigned short*)Co)[(size_t)(mb + m)*LDC + c] = (unsigned short)f2bf(h);
      } else if constexpr (EXPERT){
        const int slot = mb + m;
        float w = sw[slot];
        if (w != 0.f){
          int tok = stok[slot];
          #pragma unroll
          for (int j = 0; j < 2; ++j){
            int c = nblk*64 + (2*wn + j)*16 + r16;
            atomicAdd(&((float*)Co)[(size_t)tok*LDC + c], w * acc[i][j][r]);
          }
        }
      } else {
        #pragma unroll
        for (int j = 0; j < 2; ++j){
          int c = nblk*64 + (2*wn + j)*16 + r16;
          ((float*)Co)[(size_t)(mb + m)*LDC + c] = acc[i][j][r];
        }
      }
    }
  }
}

extern "C" void kernel_launch(void* const* d_in, const int* in_sizes, int n_in,
                              void* d_out, int out_size, void* d_ws, size_t ws_size,
                              hipStream_t stream){
  const float* x  = (const float*)d_in[0];
  const float* rw = (const float*)d_in[1];
  const float* eb = (const float*)d_in[2];
  const float* wg = (const float*)d_in[3];
  const float* wu = (const float*)d_in[4];
  const float* wd = (const float*)d_in[5];
  const float* sg = (const float*)d_in[6];
  const float* su = (const float*)d_in[7];
  const float* sd = (const float*)d_in[8];
  float* out = (float*)d_out;

  // ws layout
  char* ws = (char*)d_ws;
  unsigned short* xbf = (unsigned short*)ws; ws += (size_t)T_TOK*DIM*2;
  unsigned short* hsh = (unsigned short*)ws; ws += (size_t)T_TOK*ISH*2;
  unsigned short* hex = (unsigned short*)ws; ws += (size_t)ECAP*ISZ*2;
  unsigned short* sgb = (unsigned short*)ws; ws += (size_t)ISH*DIM*2;
  unsigned short* sub = (unsigned short*)ws; ws += (size_t)ISH*DIM*2;
  unsigned short* sdb = (unsigned short*)ws; ws += (size_t)DIM*ISH*2;
  unsigned short* wgT = (unsigned short*)ws; ws += (size_t)NEXP*ISZ*DIM*2;
  unsigned short* wuT = (unsigned short*)ws; ws += (size_t)NEXP*ISZ*DIM*2;
  unsigned short* wdT = (unsigned short*)ws; ws += (size_t)NEXP*DIM*ISZ*2;
  int*   tki  = (int*)ws;   ws += (size_t)T_TOK*TOPK*4;
  float* tkw  = (float*)ws; ws += (size_t)T_TOK*TOPK*4;
  int*   stok = (int*)ws;   ws += (size_t)ECAP*4;
  float* sw   = (float*)ws; ws += (size_t)ECAP*4;

  // activations -> bf16; router; dispatch
  cvt_k<<<(T_TOK*DIM/8)/256, 256, 0, stream>>>(x, xbf, T_TOK*DIM/8);
  router_k<<<T_TOK/4, 256, 0, stream>>>(x, rw, eb, tki, tkw);
  hipMemsetAsync(stok, 0, (size_t)ECAP*8, stream);   // stok + sw contiguous
  dispatch_k<<<2, 1024, 0, stream>>>(tki, tkw, stok, sw);

  // weights -> bf16 [N,K]
  cvt_k<<<((size_t)ISH*DIM/8)/256, 256, 0, stream>>>(sg, sgb, ISH*DIM/8);
  cvt_k<<<((size_t)ISH*DIM/8)/256, 256, 0, stream>>>(su, sub, ISH*DIM/8);
  cvt_k<<<((size_t)DIM*ISH/8)/256, 256, 0, stream>>>(sd, sdb, DIM*ISH/8);
  tcvt_k<DIM, ISZ><<<dim3(ISZ/128, DIM/128, NEXP), 256, 0, stream>>>(wg, wgT);
  tcvt_k<DIM, ISZ><<<dim3(ISZ/128, DIM/128, NEXP), 256, 0, stream>>>(wu, wuT);
  tcvt_k<ISZ, DIM><<<dim3(DIM/128, ISZ/128, NEXP), 256, 0, stream>>>(wd, wdT);

  // shared MLP: fused gate+up+silu -> hsh ; down -> out (plain store initializes d_out)
  gemm6_k<0,1><<<2048, 256, 0, stream>>>(xbf, sgb, sub, hsh, nullptr, nullptr);
  gemm6_k<0,0><<<1024, 256, 0, stream>>>(hsh, sdb, nullptr, out, nullptr, nullptr);

  // routed experts: fused gate+up+silu -> hex ; down -> atomic scaled scatter into out
  gemm6_k<1,1><<<1024, 256, 0, stream>>>(xbf, wgT, wuT, hex, stok, sw);
  gemm6_k<1,0><<<1024, 256, 0, stream>>>(hex, wdT, nullptr, out, stok, sw);
}

// Round 7
// 581.197 us; speedup vs baseline: 1.5864x; 1.5864x over previous
//
#include <hip/hip_runtime.h>
#include <math.h>

// ---------- config ----------
#define T_TOK 4096
#define DIM   2048
#define NEXP  32
#define TOPK  4
#define CAP   160          // ceil(1.25*4096/32)
#define ECAP  (NEXP*CAP)   // 5120
#define ISZ   1024         // moe intermediate
#define ISH   2048         // shared intermediate (I*NSH)

typedef short bf16x8 __attribute__((ext_vector_type(8)));
typedef float f32x4  __attribute__((ext_vector_type(4)));

__device__ __forceinline__ unsigned int f2bf(float f){
  union { float f; unsigned int u; } v; v.f = f;
  return (v.u + 0x7fffu + ((v.u >> 16) & 1u)) >> 16;   // RNE
}

// async global->LDS, 16B/lane; LDS base wave-uniform (HW adds lane*16), global addr per-lane
#define GLOAD16(g, l) __builtin_amdgcn_global_load_lds( \
    (const __attribute__((address_space(1))) unsigned int*)(g), \
    (__attribute__((address_space(3))) unsigned int*)(l), 16, 0, 0)

// ---------- fp32 -> bf16 convert (layout-preserving) ----------
__global__ __launch_bounds__(256) void cvt_k(const float* __restrict__ in,
                                             unsigned short* __restrict__ out, int n8){
  int i = blockIdx.x*256 + threadIdx.x;
  if (i >= n8) return;
  const float4 a = *(const float4*)&in[(size_t)i*8];
  const float4 b = *(const float4*)&in[(size_t)i*8 + 4];
  uint4 v;
  v.x = f2bf(a.x) | (f2bf(a.y) << 16);
  v.y = f2bf(a.z) | (f2bf(a.w) << 16);
  v.z = f2bf(b.x) | (f2bf(b.y) << 16);
  v.w = f2bf(b.z) | (f2bf(b.w) << 16);
  *(uint4*)&out[(size_t)i*8] = v;
}

// ---------- router: fp64 logits, exact top-k semantics ----------
__global__ __launch_bounds__(256) void router_k(const float* __restrict__ x,
                                                const float* __restrict__ rw,
                                                const float* __restrict__ eb,
                                                int* __restrict__ tki,
                                                float* __restrict__ tkw){
  __shared__ float  xs[4][DIM];
  __shared__ double ssh[4][NEXP];
  const int tb = blockIdx.x * 4;
  const int tid = threadIdx.x;
  for (int i = tid; i < 4*(DIM/4); i += 256){
    int t = i >> 9, c = (i & 511) << 2;
    *(float4*)&xs[t][c] = *(const float4*)&x[(size_t)(tb + t)*DIM + c];
  }
  __syncthreads();
  const int lane = tid & 63, wv = tid >> 6;
  for (int ei = 0; ei < 8; ++ei){
    int e = wv*8 + ei;
    double a0=0, a1=0, a2=0, a3=0;
    for (int d = lane; d < DIM; d += 64){
      double w = (double)rw[(size_t)e*DIM + d];
      a0 += (double)xs[0][d] * w;
      a1 += (double)xs[1][d] * w;
      a2 += (double)xs[2][d] * w;
      a3 += (double)xs[3][d] * w;
    }
    for (int off = 32; off; off >>= 1){
      a0 += __shfl_down(a0, off);
      a1 += __shfl_down(a1, off);
      a2 += __shfl_down(a2, off);
      a3 += __shfl_down(a3, off);
    }
    if (lane == 0){ ssh[0][e]=a0; ssh[1][e]=a1; ssh[2][e]=a2; ssh[3][e]=a3; }
  }
  __syncthreads();
  if (tid < 4){
    const int t = tid;
    double s[NEXP], sc[NEXP];
    for (int e = 0; e < NEXP; ++e){
      double sig = 1.0 / (1.0 + exp(-ssh[t][e]));
      s[e] = sig; sc[e] = sig + (double)eb[e];
    }
    double gsc[8];
    for (int g = 0; g < 8; ++g){
      double b0=sc[g*4],b1=sc[g*4+1],b2=sc[g*4+2],b3=sc[g*4+3];
      double h1=fmax(b0,b1), l1=fmin(b0,b1);
      double h2=fmax(b2,b3), l2=fmin(b2,b3);
      double top = fmax(h1,h2);
      double sec = fmax(fmin(h1,h2), (h1 >= h2) ? l1 : l2);
      gsc[g] = top + sec;
    }
    int gsel = 0;
    for (int r = 0; r < 3; ++r){
      int bi = -1; double bv = -1e300;
      for (int g = 0; g < 8; ++g)
        if (!((gsel >> g) & 1) && gsc[g] > bv){ bv = gsc[g]; bi = g; }
      gsel |= 1 << bi;
    }
    double mval[NEXP];
    for (int e = 0; e < NEXP; ++e)
      mval[e] = ((gsel >> (e >> 2)) & 1) ? sc[e] : 0.0;
    int idx4[4]; double wsum = 0.0, wv4[4];
    for (int r = 0; r < 4; ++r){
      int bi = -1; double bv = -1e300;
      for (int e = 0; e < NEXP; ++e)
        if (mval[e] > bv){ bv = mval[e]; bi = e; }
      idx4[r] = bi; mval[bi] = -1e300;
      wv4[r] = s[bi]; wsum += wv4[r];
    }
    const int gt = tb + t;
    for (int r = 0; r < 4; ++r){
      tki[gt*4 + r] = idx4[r];
      tkw[gt*4 + r] = (float)(wv4[r] / (wsum + 1e-20) * 2.5);
    }
  }
}

// ---------- dispatch: wave per expert, stable-order rank scan ----------
__global__ __launch_bounds__(1024) void dispatch_k(const int* __restrict__ tki,
                                                   const float* __restrict__ tkw,
                                                   int* __restrict__ stok,
                                                   float* __restrict__ sw){
  const int e = blockIdx.x*16 + (threadIdx.x >> 6);
  const int lane = threadIdx.x & 63;
  int base = 0;
  for (int it = 0; it < (T_TOK*TOPK)/64; ++it){
    if (base >= CAP) break;
    int idx = it*64 + lane;
    int ex = tki[idx];
    bool m = (ex == e);
    unsigned long long mk = __ballot(m);
    int pos = base + __popcll(mk & ((1ull << lane) - 1ull));
    if (m && pos < CAP){
      stok[e*CAP + pos] = idx >> 2;
      sw[e*CAP + pos]   = tkw[idx];
    }
    base += __popcll(mk);
  }
}

// ---------- fat-tile 8-wave MFMA GEMM (traffic-minimal) ----------
// MODE 0 EGU: hex(bf16)=silu(X@Wg)*(X@Wu); A=xbf gathered rows (stok); B=fp32 [K,1024]
//             per expert, reg-transposed; BM=160, BN=256(128g+128u paired).
// MODE 1 EDN: out += scatter(sw * (hex@Wd)); B=fp32 [K,2048]; BM=160, BN=256.
// MODE 2 SGU: hsh(bf16)=silu(X@sg^T)*(X@su^T); B=bf16 [N,K] via gload; BM=256, BN=256.
// MODE 3 SDN: out(f32, plain)=hsh@sd^T; B=bf16 [N,K]; BM=256, BN=128.
// LDS planes: 1KB = 16 cols x 32k, entry l<->(col l&15, k-oct l>>4); all ds ops
// uniform_base + lane*16 (conflict-free, matches gload_lds layout).
template<int MODE>
__global__ __launch_bounds__(512, 2)
void gemm7_k(const unsigned short* __restrict__ Ab,
             const void* __restrict__ B0v, const void* __restrict__ B1v,
             void* __restrict__ Co,
             const int* __restrict__ stok, const float* __restrict__ sw){
  constexpr int BM   = (MODE < 2) ? 160 : 256;
  constexpr int APL  = BM/16;                       // 10,10,16,16
  constexpr int FM   = BM/32;                       // 5,5,8,8
  constexpr int KK   = (MODE == 1) ? ISZ : DIM;     // 2048,1024,2048,2048
  constexpr int BPL  = (MODE == 3) ? 8 : 16;        // B planes
  constexpr int NBF  = BPL/4;                       // 4,4,4,2 B-frags per wave
  constexpr int TPL  = APL + BPL;
  constexpr int NT   = KK/32;
  constexpr int LDB  = (MODE == 0) ? ISZ : DIM;     // fp32 B n-stride (KN modes)
  constexpr int LDC  = (MODE == 0) ? ISZ : DIM;
  constexpr int SAIT = (MODE >= 2) ? (TPL+7)/8 : 2;

  __shared__ uint4 lds[2][TPL*64];

  const int tid  = threadIdx.x;
  const int lane = tid & 63, wid = tid >> 6;

  const int bid = blockIdx.x;
  int e = 0, mb = 0, nb;
  if constexpr (MODE < 2){ e = bid >> 3; nb = (bid & 7) * (MODE == 0 ? 128 : 256); }
  else if constexpr (MODE == 2){ mb = (bid & 15)*256; nb = (bid >> 4)*128; }
  else { mb = (bid & 15)*256; nb = (bid >> 4)*128; }

  // ---- gload plane pointers (A always; B too for MODE>=2) ----
  const unsigned short* gptr[SAIT];
  #pragma unroll
  for (int i = 0; i < SAIT; ++i){
    int p = wid + i*8;
    int pp = (p < ((MODE >= 2) ? TPL : APL)) ? p : 0;
    if (pp < APL){
      int r = pp*16 + (lane & 15);
      int row;
      if constexpr (MODE == 0)      row = stok[e*CAP + r];
      else if constexpr (MODE == 1) row = e*CAP + r;
      else                          row = mb + r;
      gptr[i] = Ab + (size_t)row*KK + (lane >> 4)*8;
    } else {
      int q = pp - APL;
      const unsigned short* src = (const unsigned short*)B0v;
      int n;
      if constexpr (MODE == 2){ if (q & 1) src = (const unsigned short*)B1v;
                                n = nb + (q >> 1)*16 + (lane & 15); }
      else                    { n = nb + q*16 + (lane & 15); }
      gptr[i] = src + (size_t)n*KK + (lane >> 4)*8;
    }
  }
  auto stageG = [&](int k0, int buf){
    char* base = (char*)&lds[buf][0];
    #pragma unroll
    for (int i = 0; i < SAIT; ++i){
      int p = wid + i*8;
      if (p < ((MODE >= 2) ? TPL : APL))
        GLOAD16(gptr[i] + k0, base + p*1024);
    }
  };

  // ---- fp32 B reg-staging (MODE<=1): thread = (oct, col-pair) ----
  const int oct = tid >> 7, pi = tid & 127, c0 = pi*2;
  const float* bkn = nullptr;
  if constexpr (MODE == 0){
    int q = c0 >> 4;
    const float* src = (const float*)((q & 1) ? B1v : B0v);
    int n0 = nb + (q >> 1)*16 + (c0 & 15);
    bkn = src + (size_t)e*KK*LDB + (size_t)oct*8*LDB + n0;
  } else if constexpr (MODE == 1){
    bkn = (const float*)B0v + (size_t)e*KK*LDB + (size_t)oct*8*LDB + (nb + c0);
  }
  float2 br2[8];
  auto loadB = [&](int k0){
    const float* p = bkn + (size_t)k0*LDB;
    #pragma unroll
    for (int j = 0; j < 8; ++j) br2[j] = *(const float2*)(p + (size_t)j*LDB);
  };
  auto writeB = [&](int buf){
    char* base = (char*)&lds[buf][0] + (size_t)APL*1024;
    uint4 vx, vy;
    vx.x = f2bf(br2[0].x)|(f2bf(br2[1].x)<<16); vx.y = f2bf(br2[2].x)|(f2bf(br2[3].x)<<16);
    vx.z = f2bf(br2[4].x)|(f2bf(br2[5].x)<<16); vx.w = f2bf(br2[6].x)|(f2bf(br2[7].x)<<16);
    vy.x = f2bf(br2[0].y)|(f2bf(br2[1].y)<<16); vy.y = f2bf(br2[2].y)|(f2bf(br2[3].y)<<16);
    vy.z = f2bf(br2[4].y)|(f2bf(br2[5].y)<<16); vy.w = f2bf(br2[6].y)|(f2bf(br2[7].y)<<16);
    char* d = base + (c0 >> 4)*1024 + oct*256 + (c0 & 15)*16;
    *(uint4*)d = vx;
    *(uint4*)(d + 16) = vy;
  };

  // ---- compute-side assignment: 8 waves = 2m x 4n ----
  const int wmp = (wid >> 2) * FM;          // first A plane
  const int wq  = wid & 3;                  // n-wave
  f32x4 acc[FM][NBF];
  #pragma unroll
  for (int i = 0; i < FM; ++i)
    #pragma unroll
    for (int j = 0; j < NBF; ++j) acc[i][j] = f32x4{0,0,0,0};

  // prologue
  if constexpr (MODE <= 1) loadB(0);
  stageG(0, 0);
  if constexpr (MODE <= 1) writeB(0);
  __syncthreads();

  for (int t = 0; t < NT; ++t){
    const int cur = t & 1;
    if (t + 1 < NT){
      if constexpr (MODE <= 1) loadB((t+1)*32);
      stageG((t+1)*32, cur^1);
    }
    const char* L = (const char*)&lds[cur][0];
    bf16x8 af[FM], bfr[NBF];
    #pragma unroll
    for (int i = 0; i < FM; ++i)
      af[i] = *(const bf16x8*)(L + (wmp + i)*1024 + lane*16);
    #pragma unroll
    for (int j = 0; j < NBF; ++j)
      bfr[j] = *(const bf16x8*)(L + (APL + wq*NBF + j)*1024 + lane*16);
    #pragma unroll
    for (int i = 0; i < FM; ++i)
      #pragma unroll
      for (int j = 0; j < NBF; ++j)
        acc[i][j] = __builtin_amdgcn_mfma_f32_16x16x32_bf16(af[i], bfr[j], acc[i][j], 0, 0, 0);
    if constexpr (MODE <= 1){ if (t + 1 < NT) writeB(cur^1); }
    __syncthreads();
  }

  // ---- epilogue ----
  const int cl = lane & 15, rg = (lane >> 4)*4;
  #pragma unroll
  for (int i = 0; i < FM; ++i){
    #pragma unroll
    for (int r = 0; r < 4; ++r){
      const int m = (wid >> 2)*(BM/2) + i*16 + rg + r;
      if constexpr (MODE == 0 || MODE == 2){
        // paired planes: even=gate, odd=up, same cols
        #pragma unroll
        for (int jj = 0; jj < 2; ++jj){
          float g = acc[i][jj*2][r], u = acc[i][jj*2+1][r];
          float h = g / (1.f + __expf(-g)) * u;
          int gcol = nb + wq*32 + jj*16 + cl;
          size_t row = (MODE == 0) ? (size_t)(e*CAP + m) : (size_t)(mb + m);
          ((unsigned short*)Co)[row*LDC + gcol] = (unsigned short)f2bf(h);
        }
      } else if constexpr (MODE == 1){
        const int slot = e*CAP + m;
        float w = sw[slot];
        if (w != 0.f){
          int tok = stok[slot];
          #pragma unroll
          for (int j = 0; j < 4; ++j){
            int c = nb + wq*64 + j*16 + cl;
            atomicAdd(&((float*)Co)[(size_t)tok*DIM + c], w * acc[i][j][r]);
          }
        }
      } else {
        #pragma unroll
        for (int j = 0; j < 2; ++j){
          int c = nb + wq*32 + j*16 + cl;
          ((float*)Co)[(size_t)(mb + m)*DIM + c] = acc[i][j][r];
        }
      }
    }
  }
}

extern "C" void kernel_launch(void* const* d_in, const int* in_sizes, int n_in,
                              void* d_out, int out_size, void* d_ws, size_t ws_size,
                              hipStream_t stream){
  const float* x  = (const float*)d_in[0];
  const float* rw = (const float*)d_in[1];
  const float* eb = (const float*)d_in[2];
  const float* wg = (const float*)d_in[3];
  const float* wu = (const float*)d_in[4];
  const float* wd = (const float*)d_in[5];
  const float* sg = (const float*)d_in[6];
  const float* su = (const float*)d_in[7];
  const float* sd = (const float*)d_in[8];
  float* out = (float*)d_out;

  char* ws = (char*)d_ws;
  unsigned short* xbf = (unsigned short*)ws; ws += (size_t)T_TOK*DIM*2;
  unsigned short* hsh = (unsigned short*)ws; ws += (size_t)T_TOK*ISH*2;
  unsigned short* hex = (unsigned short*)ws; ws += (size_t)ECAP*ISZ*2;
  unsigned short* sgb = (unsigned short*)ws; ws += (size_t)ISH*DIM*2;
  unsigned short* sub = (unsigned short*)ws; ws += (size_t)ISH*DIM*2;
  unsigned short* sdb = (unsigned short*)ws; ws += (size_t)DIM*ISH*2;
  int*   tki  = (int*)ws;   ws += (size_t)T_TOK*TOPK*4;
  float* tkw  = (float*)ws; ws += (size_t)T_TOK*TOPK*4;
  int*   stok = (int*)ws;   ws += (size_t)ECAP*4;
  float* sw   = (float*)ws; ws += (size_t)ECAP*4;

  // activations + shared weights -> bf16; router; dispatch
  cvt_k<<<(T_TOK*DIM/8)/256, 256, 0, stream>>>(x, xbf, T_TOK*DIM/8);
  cvt_k<<<((size_t)ISH*DIM/8)/256, 256, 0, stream>>>(sg, sgb, ISH*DIM/8);
  cvt_k<<<((size_t)ISH*DIM/8)/256, 256, 0, stream>>>(su, sub, ISH*DIM/8);
  cvt_k<<<((size_t)DIM*ISH/8)/256, 256, 0, stream>>>(sd, sdb, DIM*ISH/8);
  router_k<<<T_TOK/4, 256, 0, stream>>>(x, rw, eb, tki, tkw);
  hipMemsetAsync(stok, 0, (size_t)ECAP*8, stream);   // stok + sw contiguous
  dispatch_k<<<2, 1024, 0, stream>>>(tki, tkw, stok, sw);

  // shared MLP (B via gload, bf16): gate+up+silu -> hsh ; down -> out (plain store inits)
  gemm7_k<2><<<256, 512, 0, stream>>>(xbf, sgb, sub, hsh, nullptr, nullptr);
  gemm7_k<3><<<256, 512, 0, stream>>>(hsh, sdb, nullptr, out, nullptr, nullptr);

  // routed experts (B = fp32 weights read once, reg-transposed)
  gemm7_k<0><<<256, 512, 0, stream>>>(xbf, wg, wu, hex, stok, sw);
  gemm7_k<1><<<256, 512, 0, stream>>>(hex, wd, nullptr, out, stok, sw);
}

// Round 8
// 532.898 us; speedup vs baseline: 1.7301x; 1.0906x over previous
//
#include <hip/hip_runtime.h>
#include <math.h>

// ---------- config ----------
#define T_TOK 4096
#define DIM   2048
#define NEXP  32
#define TOPK  4
#define CAP   160          // ceil(1.25*4096/32)
#define ECAP  (NEXP*CAP)   // 5120
#define ISZ   1024         // moe intermediate
#define ISH   2048         // shared intermediate (I*NSH)

typedef short bf16x8 __attribute__((ext_vector_type(8)));
typedef float f32x4  __attribute__((ext_vector_type(4)));

__device__ __forceinline__ unsigned int f2bf(float f){
  union { float f; unsigned int u; } v; v.f = f;
  return (v.u + 0x7fffu + ((v.u >> 16) & 1u)) >> 16;   // RNE
}

// async global->LDS, 16B/lane; LDS base wave-uniform (HW adds lane*16), global addr per-lane
#define GLOAD16(g, l) __builtin_amdgcn_global_load_lds( \
    (const __attribute__((address_space(1))) unsigned int*)(g), \
    (__attribute__((address_space(3))) unsigned int*)(l), 16, 0, 0)

// ---------- fp32 -> bf16 convert (layout-preserving) ----------
__global__ __launch_bounds__(256) void cvt_k(const float* __restrict__ in,
                                             unsigned short* __restrict__ out, int n8){
  int i = blockIdx.x*256 + threadIdx.x;
  if (i >= n8) return;
  const float4 a = *(const float4*)&in[(size_t)i*8];
  const float4 b = *(const float4*)&in[(size_t)i*8 + 4];
  uint4 v;
  v.x = f2bf(a.x) | (f2bf(a.y) << 16);
  v.y = f2bf(a.z) | (f2bf(a.w) << 16);
  v.z = f2bf(b.x) | (f2bf(b.y) << 16);
  v.w = f2bf(b.z) | (f2bf(b.w) << 16);
  *(uint4*)&out[(size_t)i*8] = v;
}

// ---------- router: fp64 logits, exact top-k semantics ----------
__global__ __launch_bounds__(256) void router_k(const float* __restrict__ x,
                                                const float* __restrict__ rw,
                                                const float* __restrict__ eb,
                                                int* __restrict__ tki,
                                                float* __restrict__ tkw){
  __shared__ float  xs[4][DIM];
  __shared__ double ssh[4][NEXP];
  const int tb = blockIdx.x * 4;
  const int tid = threadIdx.x;
  for (int i = tid; i < 4*(DIM/4); i += 256){
    int t = i >> 9, c = (i & 511) << 2;
    *(float4*)&xs[t][c] = *(const float4*)&x[(size_t)(tb + t)*DIM + c];
  }
  __syncthreads();
  const int lane = tid & 63, wv = tid >> 6;
  for (int ei = 0; ei < 8; ++ei){
    int e = wv*8 + ei;
    double a0=0, a1=0, a2=0, a3=0;
    for (int d = lane; d < DIM; d += 64){
      double w = (double)rw[(size_t)e*DIM + d];
      a0 += (double)xs[0][d] * w;
      a1 += (double)xs[1][d] * w;
      a2 += (double)xs[2][d] * w;
      a3 += (double)xs[3][d] * w;
    }
    for (int off = 32; off; off >>= 1){
      a0 += __shfl_down(a0, off);
      a1 += __shfl_down(a1, off);
      a2 += __shfl_down(a2, off);
      a3 += __shfl_down(a3, off);
    }
    if (lane == 0){ ssh[0][e]=a0; ssh[1][e]=a1; ssh[2][e]=a2; ssh[3][e]=a3; }
  }
  __syncthreads();
  if (tid < 4){
    const int t = tid;
    double s[NEXP], sc[NEXP];
    for (int e = 0; e < NEXP; ++e){
      double sig = 1.0 / (1.0 + exp(-ssh[t][e]));
      s[e] = sig; sc[e] = sig + (double)eb[e];
    }
    double gsc[8];
    for (int g = 0; g < 8; ++g){
      double b0=sc[g*4],b1=sc[g*4+1],b2=sc[g*4+2],b3=sc[g*4+3];
      double h1=fmax(b0,b1), l1=fmin(b0,b1);
      double h2=fmax(b2,b3), l2=fmin(b2,b3);
      double top = fmax(h1,h2);
      double sec = fmax(fmin(h1,h2), (h1 >= h2) ? l1 : l2);
      gsc[g] = top + sec;
    }
    int gsel = 0;
    for (int r = 0; r < 3; ++r){
      int bi = -1; double bv = -1e300;
      for (int g = 0; g < 8; ++g)
        if (!((gsel >> g) & 1) && gsc[g] > bv){ bv = gsc[g]; bi = g; }
      gsel |= 1 << bi;
    }
    double mval[NEXP];
    for (int e = 0; e < NEXP; ++e)
      mval[e] = ((gsel >> (e >> 2)) & 1) ? sc[e] : 0.0;
    int idx4[4]; double wsum = 0.0, wv4[4];
    for (int r = 0; r < 4; ++r){
      int bi = -1; double bv = -1e300;
      for (int e = 0; e < NEXP; ++e)
        if (mval[e] > bv){ bv = mval[e]; bi = e; }
      idx4[r] = bi; mval[bi] = -1e300;
      wv4[r] = s[bi]; wsum += wv4[r];
    }
    const int gt = tb + t;
    for (int r = 0; r < 4; ++r){
      tki[gt*4 + r] = idx4[r];
      tkw[gt*4 + r] = (float)(wv4[r] / (wsum + 1e-20) * 2.5);
    }
  }
}

// ---------- dispatch: wave per expert, stable-order rank scan ----------
__global__ __launch_bounds__(1024) void dispatch_k(const int* __restrict__ tki,
                                                   const float* __restrict__ tkw,
                                                   int* __restrict__ stok,
                                                   float* __restrict__ sw){
  const int e = blockIdx.x*16 + (threadIdx.x >> 6);
  const int lane = threadIdx.x & 63;
  int base = 0;
  for (int it = 0; it < (T_TOK*TOPK)/64; ++it){
    if (base >= CAP) break;
    int idx = it*64 + lane;
    int ex = tki[idx];
    bool m = (ex == e);
    unsigned long long mk = __ballot(m);
    int pos = base + __popcll(mk & ((1ull << lane) - 1ull));
    if (m && pos < CAP){
      stok[e*CAP + pos] = idx >> 2;
      sw[e*CAP + pos]   = tkw[idx];
    }
    base += __popcll(mk);
  }
}

// ---------- fat-tile 8-wave MFMA GEMM, 3-deep counted-vmcnt pipeline ----------
// MODE 0 EGU: hex(bf16)=silu(X@Wg)*(X@Wu); A gathered (stok); B fp32 [K,1024] reg-staged.
// MODE 1 EDN: out += scatter(sw*(hex@Wd)); B fp32 [K,2048] reg-staged.
// MODE 2 SGU: hsh(bf16)=silu(X@sg^T)*(X@su^T); both operands bf16 via gload.
// MODE 3 SDN: out(f32 plain)=hsh@sd^T; both bf16 via gload.
// Pipeline: stage(t+2) issued at top of step t; per-wave counted s_waitcnt vmcnt(K)
// (K = own loads/step) + raw s_barrier; never drains to 0 mid-loop. fp32-B path:
// loadB(t+2)->regs early, writeB(t+1) after MFMA (T14); 2 named reg sets, unroll-2.
template<int MODE>
__global__ __launch_bounds__(512, 2)
void gemm8_k(const unsigned short* __restrict__ Ab,
             const void* __restrict__ B0v, const void* __restrict__ B1v,
             void* __restrict__ Co,
             const int* __restrict__ stok, const float* __restrict__ sw){
  constexpr int BM   = (MODE < 2) ? 160 : 256;
  constexpr int APL  = BM/16;                       // 10,10,16,16
  constexpr int FM   = BM/32;                       // 5,5,8,8
  constexpr int KK   = (MODE == 1) ? ISZ : DIM;
  constexpr int BPL  = (MODE == 3) ? 8 : 16;        // B planes
  constexpr int NBF  = BPL/4;                       // B frags per wave (4,4,4,2)
  constexpr int TPL  = APL + BPL;                   // 26,26,32,24
  constexpr int NT   = KK/32;                       // 64,32,64,64 (all even)
  constexpr int LDB  = (MODE == 0) ? ISZ : DIM;     // fp32 B n-stride
  constexpr int LDC  = (MODE == 0) ? ISZ : DIM;
  constexpr int SAIT = (MODE >= 2) ? (TPL+7)/8 : 2;

  __shared__ uint4 lds[3][TPL*64];

  const int tid  = threadIdx.x;
  const int lane = tid & 63, wid = tid >> 6;

  const int bid = blockIdx.x;
  int e = 0, mb = 0, nb;
  if constexpr (MODE < 2){
    // XCD-aware: blocks with bid%8==x are experts 4x..4x+3 -> same-XCD A-tile reuse
    const int x = bid & 7, s = bid >> 3;
    e  = x*4 + (s & 3);
    nb = (s >> 2) * (MODE == 0 ? 128 : 256);
  } else {
    mb = (bid & 15)*256; nb = (bid >> 4)*128;
  }

  // ---- gload plane pointers (A always; B too for MODE>=2) ----
  const unsigned short* gptr[SAIT];
  #pragma unroll
  for (int i = 0; i < SAIT; ++i){
    int p = wid + i*8;
    int pp = (p < ((MODE >= 2) ? TPL : APL)) ? p : 0;
    if (pp < APL){
      int r = pp*16 + (lane & 15);
      int row;
      if constexpr (MODE == 0)      row = stok[e*CAP + r];
      else if constexpr (MODE == 1) row = e*CAP + r;
      else                          row = mb + r;
      gptr[i] = Ab + (size_t)row*KK + (lane >> 4)*8;
    } else {
      int q = pp - APL;
      const unsigned short* src = (const unsigned short*)B0v;
      int n;
      if constexpr (MODE == 2){ if (q & 1) src = (const unsigned short*)B1v;
                                n = nb + (q >> 1)*16 + (lane & 15); }
      else                    { n = nb + q*16 + (lane & 15); }
      gptr[i] = src + (size_t)n*KK + (lane >> 4)*8;
    }
  }
  auto stageG = [&](int k0, int buf){
    char* base = (char*)&lds[buf][0];
    #pragma unroll
    for (int i = 0; i < SAIT; ++i){
      int p = wid + i*8;
      if (p < ((MODE >= 2) ? TPL : APL))
        GLOAD16(gptr[i] + k0, base + p*1024);
    }
  };

  // ---- fp32 B reg-staging (MODE<=1): thread = (k-oct, col-pair) ----
  const int oct = tid >> 7, c0 = (tid & 127)*2;
  const float* bkn = nullptr;
  if constexpr (MODE == 0){
    int q = c0 >> 4;
    const float* src = (const float*)((q & 1) ? B1v : B0v);
    int n0 = nb + (q >> 1)*16 + (c0 & 15);
    bkn = src + (size_t)e*KK*LDB + (size_t)oct*8*LDB + n0;
  } else if constexpr (MODE == 1){
    bkn = (const float*)B0v + (size_t)e*KK*LDB + (size_t)oct*8*LDB + (nb + c0);
  }
  auto loadB = [&](int k0, float2 (&br)[8]){
    const float* p = bkn + (size_t)k0*LDB;
    #pragma unroll
    for (int j = 0; j < 8; ++j) br[j] = *(const float2*)(p + (size_t)j*LDB);
  };
  auto writeB = [&](int buf, const float2 (&br)[8]){
    char* base = (char*)&lds[buf][0] + (size_t)APL*1024;
    uint4 vx, vy;
    vx.x = f2bf(br[0].x)|(f2bf(br[1].x)<<16); vx.y = f2bf(br[2].x)|(f2bf(br[3].x)<<16);
    vx.z = f2bf(br[4].x)|(f2bf(br[5].x)<<16); vx.w = f2bf(br[6].x)|(f2bf(br[7].x)<<16);
    vy.x = f2bf(br[0].y)|(f2bf(br[1].y)<<16); vy.y = f2bf(br[2].y)|(f2bf(br[3].y)<<16);
    vy.z = f2bf(br[4].y)|(f2bf(br[5].y)<<16); vy.w = f2bf(br[6].y)|(f2bf(br[7].y)<<16);
    char* d = base + (c0 >> 4)*1024 + oct*256 + (c0 & 15)*16;
    *(uint4*)d = vx;
    *(uint4*)(d + 16) = vy;
  };

  // counted waits: K = own loads issued per step (stage Sw + 8 reg-B loads)
  auto waitK = [&]{
    if constexpr (MODE <= 1){
      if (wid < 2) asm volatile("s_waitcnt vmcnt(10)" ::: "memory");
      else         asm volatile("s_waitcnt vmcnt(9)"  ::: "memory");
      asm volatile("s_waitcnt lgkmcnt(0)" ::: "memory");
    } else if constexpr (MODE == 2){
      asm volatile("s_waitcnt vmcnt(4)" ::: "memory");
    } else {
      asm volatile("s_waitcnt vmcnt(3)" ::: "memory");
    }
  };

  // ---- compute-side assignment: 8 waves = 2m x 4n ----
  const int wmp = (wid >> 2) * FM;
  const int wq  = wid & 3;
  f32x4 acc[FM][NBF];
  #pragma unroll
  for (int i = 0; i < FM; ++i)
    #pragma unroll
    for (int j = 0; j < NBF; ++j) acc[i][j] = f32x4{0,0,0,0};

  float2 brA[8], brB[8];

  // ---- prologue: two stages in flight ----
  stageG(0, 0);
  if constexpr (MODE <= 1) loadB(0, brA);
  stageG(32, 1);
  if constexpr (MODE <= 1){ loadB(32, brB); writeB(0, brA); }
  waitK();
  __builtin_amdgcn_s_barrier();

  int cons = 0;
  auto step = [&](int t, float2 (&brW)[8], float2 (&brL)[8]){
    const int stg = (cons >= 1) ? cons - 1 : 2;         // (cons+2)%3
    const int nxt = (cons == 2) ? 0 : cons + 1;
    if (t + 2 < NT){
      stageG((t+2)*32, stg);
      if constexpr (MODE <= 1) loadB((t+2)*32, brL);
    }
    __builtin_amdgcn_sched_barrier(0);                  // pin issues early
    const char* L = (const char*)&lds[cons][0];
    bf16x8 af[FM], bfr[NBF];
    #pragma unroll
    for (int i = 0; i < FM; ++i)
      af[i] = *(const bf16x8*)(L + (wmp + i)*1024 + lane*16);
    #pragma unroll
    for (int j = 0; j < NBF; ++j)
      bfr[j] = *(const bf16x8*)(L + (APL + wq*NBF + j)*1024 + lane*16);
    #pragma unroll
    for (int i = 0; i < FM; ++i)
      #pragma unroll
      for (int j = 0; j < NBF; ++j)
        acc[i][j] = __builtin_amdgcn_mfma_f32_16x16x32_bf16(af[i], bfr[j], acc[i][j], 0, 0, 0);
    if constexpr (MODE <= 1){
      if (t + 1 < NT) writeB(nxt, brW);
    }
    if (t + 2 < NT){
      waitK();                                          // leave t+2 batch in flight
    } else if (t == NT - 2){
      asm volatile("s_waitcnt vmcnt(0)" ::: "memory");
      if constexpr (MODE <= 1) asm volatile("s_waitcnt lgkmcnt(0)" ::: "memory");
    }
    if (t < NT - 1) __builtin_amdgcn_s_barrier();
    cons = nxt;
  };

  for (int t2 = 0; t2 < NT/2; ++t2){
    step(2*t2,     brB, brA);
    step(2*t2 + 1, brA, brB);
  }

  // ---- epilogue ----
  const int cl = lane & 15, rg = (lane >> 4)*4;
  #pragma unroll
  for (int i = 0; i < FM; ++i){
    #pragma unroll
    for (int r = 0; r < 4; ++r){
      const int m = (wid >> 2)*(BM/2) + i*16 + rg + r;
      if constexpr (MODE == 0 || MODE == 2){
        #pragma unroll
        for (int jj = 0; jj < 2; ++jj){
          float g = acc[i][jj*2][r], u = acc[i][jj*2+1][r];
          float h = g / (1.f + __expf(-g)) * u;
          int gcol = nb + wq*32 + jj*16 + cl;
          size_t row = (MODE == 0) ? (size_t)(e*CAP + m) : (size_t)(mb + m);
          ((unsigned short*)Co)[row*LDC + gcol] = (unsigned short)f2bf(h);
        }
      } else if constexpr (MODE == 1){
        const int slot = e*CAP + m;
        float w = sw[slot];
        if (w != 0.f){
          int tok = stok[slot];
          #pragma unroll
          for (int j = 0; j < 4; ++j){
            int c = nb + wq*64 + j*16 + cl;
            atomicAdd(&((float*)Co)[(size_t)tok*DIM + c], w * acc[i][j][r]);
          }
        }
      } else {
        #pragma unroll
        for (int j = 0; j < 2; ++j){
          int c = nb + wq*32 + j*16 + cl;
          ((float*)Co)[(size_t)(mb + m)*DIM + c] = acc[i][j][r];
        }
      }
    }
  }
}

extern "C" void kernel_launch(void* const* d_in, const int* in_sizes, int n_in,
                              void* d_out, int out_size, void* d_ws, size_t ws_size,
                              hipStream_t stream){
  const float* x  = (const float*)d_in[0];
  const float* rw = (const float*)d_in[1];
  const float* eb = (const float*)d_in[2];
  const float* wg = (const float*)d_in[3];
  const float* wu = (const float*)d_in[4];
  const float* wd = (const float*)d_in[5];
  const float* sg = (const float*)d_in[6];
  const float* su = (const float*)d_in[7];
  const float* sd = (const float*)d_in[8];
  float* out = (float*)d_out;

  char* ws = (char*)d_ws;
  unsigned short* xbf = (unsigned short*)ws; ws += (size_t)T_TOK*DIM*2;
  unsigned short* hsh = (unsigned short*)ws; ws += (size_t)T_TOK*ISH*2;
  unsigned short* hex = (unsigned short*)ws; ws += (size_t)ECAP*ISZ*2;
  unsigned short* sgb = (unsigned short*)ws; ws += (size_t)ISH*DIM*2;
  unsigned short* sub = (unsigned short*)ws; ws += (size_t)ISH*DIM*2;
  unsigned short* sdb = (unsigned short*)ws; ws += (size_t)DIM*ISH*2;
  int*   tki  = (int*)ws;   ws += (size_t)T_TOK*TOPK*4;
  float* tkw  = (float*)ws; ws += (size_t)T_TOK*TOPK*4;
  int*   stok = (int*)ws;   ws += (size_t)ECAP*4;
  float* sw   = (float*)ws; ws += (size_t)ECAP*4;

  // activations + shared weights -> bf16; router; dispatch
  cvt_k<<<(T_TOK*DIM/8)/256, 256, 0, stream>>>(x, xbf, T_TOK*DIM/8);
  cvt_k<<<((size_t)ISH*DIM/8)/256, 256, 0, stream>>>(sg, sgb, ISH*DIM/8);
  cvt_k<<<((size_t)ISH*DIM/8)/256, 256, 0, stream>>>(su, sub, ISH*DIM/8);
  cvt_k<<<((size_t)DIM*ISH/8)/256, 256, 0, stream>>>(sd, sdb, DIM*ISH/8);
  router_k<<<T_TOK/4, 256, 0, stream>>>(x, rw, eb, tki, tkw);
  hipMemsetAsync(stok, 0, (size_t)ECAP*8, stream);   // stok + sw contiguous
  dispatch_k<<<2, 1024, 0, stream>>>(tki, tkw, stok, sw);

  // shared MLP: gate+up+silu -> hsh ; down -> out (plain store initializes d_out)
  gemm8_k<2><<<256, 512, 0, stream>>>(xbf, sgb, sub, hsh, nullptr, nullptr);
  gemm8_k<3><<<256, 512, 0, stream>>>(hsh, sdb, nullptr, out, nullptr, nullptr);

  // routed experts (B = fp32 weights read once, reg-transposed)
  gemm8_k<0><<<256, 512, 0, stream>>>(xbf, wg, wu, hex, stok, sw);
  gemm8_k<1><<<256, 512, 0, stream>>>(hex, wd, nullptr, out, stok, sw);
}